// Round 2
// baseline (299.055 us; speedup 1.0000x reference)
//
#include <hip/hip_runtime.h>
#include <hip/hip_bf16.h>
#include <stdint.h>

// FPNAttentionV2 v2: single-barrier full-K GEMM blocks, frag-major weights (B bypasses LDS),
// split-K kdown with atomics, vectorized NCHW->NHWC transpose.

typedef __attribute__((ext_vector_type(8))) __bf16 bf16x8;
typedef __attribute__((ext_vector_type(4))) float f32x4;
typedef __attribute__((ext_vector_type(8))) unsigned short u16x8;

typedef const __attribute__((address_space(1))) uint32_t* gptr_t;
typedef __attribute__((address_space(3))) uint32_t* lptr_t;

__device__ __forceinline__ void cp16(void* lds, const void* g) {
  // async global->LDS, 16B/lane; LDS dest must be wave-uniform (HW adds lane*16)
  gptr_t gp = reinterpret_cast<gptr_t>(reinterpret_cast<uintptr_t>(g));
  lptr_t lp = reinterpret_cast<lptr_t>(
      static_cast<uint32_t>(reinterpret_cast<uintptr_t>(lds)));
  __builtin_amdgcn_global_load_lds(gp, lp, 16, 0, 0);
}

// ---------------- NCHW f32 -> NHWC bf16 (optionally +1 zero pad ring) ----------------
// grid: x = W/64, y = 4 (c-tiles), z = B*H ; block 256
__global__ void nchw2nhwc_v2(const float* __restrict__ src,
                             uint16_t* __restrict__ dst,
                             int H, int W, int pad) {
  __shared__ float tile[64][65];  // [c][w], stride 65 -> conflict-free
  const int tid = threadIdx.x;
  const int b = blockIdx.z / H;
  const int h = blockIdx.z - b * H;
  const int wt = blockIdx.x * 64;
  const int ct = blockIdx.y * 64;
  const long cs = (long)H * W;
  const float* s = src + ((long)(b * 256 + ct) * H + h) * W + wt;
  const int rw = tid >> 4;   // 0..15 (c row within pass)
  const int rf = tid & 15;   // float4 index along w
#pragma unroll
  for (int p = 0; p < 4; p++) {
    const int cl = p * 16 + rw;
    const float4 v = *(const float4*)(s + (long)cl * cs + rf * 4);
    tile[cl][rf * 4 + 0] = v.x;
    tile[cl][rf * 4 + 1] = v.y;
    tile[cl][rf * 4 + 2] = v.z;
    tile[cl][rf * 4 + 3] = v.w;
  }
  __syncthreads();
  const int wl0 = tid >> 3;  // 0..31
  const int cg = tid & 7;    // 8-channel group
  const int Wp = W + 2 * pad;
  const long rowb = ((long)(b * (H + 2 * pad) + h + pad)) * Wp + pad + wt;
#pragma unroll
  for (int p = 0; p < 2; p++) {
    const int wl = p * 32 + wl0;
    u16x8 u;
#pragma unroll
    for (int k = 0; k < 8; k++) {
      __hip_bfloat16 hb = __float2bfloat16(tile[cg * 8 + k][wl]);
      u[k] = *reinterpret_cast<uint16_t*>(&hb);
    }
    *(u16x8*)(dst + (rowb + wl) * 256 + ct + cg * 8) = u;
  }
}

// ---------------- weights f32 -> bf16, FRAGMENT-MAJOR layout ----------------
// Per matrix (65536 elems): [jg(16)][kc(8)][lane(64)][e(8)]
//   o = jg*16 + (lane&15), k = kc*32 + (lane>>4)*8 + e
// Matrices 0..6: q1,q2,ks1,ks2,kup,v1,v2 ; 7..15: kdown taps 0..8
struct WArgs {
  const float* w1[7];
  const float* kdw;  // [256][256][3][3]
};

__global__ void convert_weights_v2(WArgs a, uint16_t* __restrict__ wf) {
  const int idx = blockIdx.x * 256 + threadIdx.x;  // 131072 threads
  const int mat = idx >> 13;
  const int g = idx & 8191;
  const int jg = g >> 9;
  const int kc = (g >> 6) & 7;
  const int lane = g & 63;
  const int o = jg * 16 + (lane & 15);
  const int k0 = kc * 32 + (lane >> 4) * 8;
  float f[8];
  if (mat < 7) {
    const float* w = a.w1[mat];
    const float4 v0 = *(const float4*)(w + o * 256 + k0);
    const float4 v1 = *(const float4*)(w + o * 256 + k0 + 4);
    f[0] = v0.x; f[1] = v0.y; f[2] = v0.z; f[3] = v0.w;
    f[4] = v1.x; f[5] = v1.y; f[6] = v1.z; f[7] = v1.w;
  } else {
    const int tap = mat - 7;
#pragma unroll
    for (int e = 0; e < 8; e++)
      f[e] = a.kdw[(long)o * 2304 + (long)(k0 + e) * 9 + tap];
  }
  u16x8 u;
#pragma unroll
  for (int e = 0; e < 8; e++) {
    __hip_bfloat16 hb = __float2bfloat16(f[e]);
    u[e] = *reinterpret_cast<uint16_t*>(&hb);
  }
  *(u16x8*)(wf + (long)idx * 8) = u;
}

// ---------------- fused GEMM ----------------
struct Job {
  const uint16_t* A;   // bf16 NHWC activations (x1 padded, or x2)
  const uint16_t* Wf;  // frag-major bf16 weights (mode 3: base of 9 tap matrices)
  const float* bias;   // f32 (nullptr -> no bias; kdown groups 1,2)
  float* out;          // f32 NHWC
  int mtiles;
  int mode;  // 0: x1 1x1 (padded addr), 1: x2 1x1, 2: x2 + 2x upsample, 3: kdown tap-group (atomic)
  int tap0;
};
struct JobArgs {
  Job j[10];
};

// block 256 = 4 waves (2x2); tile 128 rows x 256 cols; full K staged in LDS once.
// LDS A layout: [kc(8)][row(128)][32 elems]  (K-sliced m97 geometry, 64B rows)
__global__ __launch_bounds__(256, 2) void fused_gemm(JobArgs args) {
  const Job jb = args.j[blockIdx.z];
  if ((int)blockIdx.x >= jb.mtiles) return;
  const int mtile = blockIdx.x;
  const int mode = jb.mode;

  __shared__ __align__(16) uint16_t lA[32768];  // 64KB

  const int tid = threadIdx.x;
  const int lane = tid & 63;
  const int wave = tid >> 6;
  const int wr = wave & 1;   // m-half (64 rows)
  const int wc = wave >> 1;  // n-half (128 cols)
  const int q = lane >> 4;
  const int l15 = lane & 15;

  // staging source row pointers (per-lane), rhalf 0/1
  const uint16_t* rowA[2];
  {
    const int rbase = wave * 16 + (lane >> 2);
#pragma unroll
    for (int rh = 0; rh < 2; rh++) {
      const int m = mtile * 128 + rh * 64 + rbase;
      long p;
      if (mode == 0) {
        p = ((long)((m >> 14) * 130 + ((m >> 7) & 127) + 1)) * 130 + (m & 127) + 1;
      } else if (mode == 3) {
        p = ((long)((m >> 12) * 130 + 2 * ((m >> 6) & 63))) * 130 + 2 * (m & 63);
      } else {
        p = m;
      }
      rowA[rh] = jb.A + p * 256 + (lane & 3) * 8;
    }
  }

  f32x4 acc[4][8] = {};
  const int ntaps = (mode == 3) ? 3 : 1;

  for (int t = 0; t < ntaps; t++) {
    long aoff = 0;
    const uint16_t* wf = jb.Wf;
    if (mode == 3) {
      const int tap = jb.tap0 + t;
      const int kh = tap / 3;
      const int kw = tap - kh * 3;
      aoff = (long)(kh * 130 + kw) * 256;
      wf = jb.Wf + (long)tap * 65536;
    }
    if (t) __syncthreads();  // prior tap's LDS reads done before overwrite
    // stage 64KB: chunk cid = kap*256 + wave*64 + lane -> [kc=cid>>9][row=(cid>>2)&127][16B=cid&3]
#pragma unroll
    for (int kap = 0; kap < 16; kap++) {
      const uint16_t* src = rowA[kap & 1] + aoff + (kap >> 1) * 32;
      cp16(lA + (kap * 256 + wave * 64) * 8, src);
    }
    __syncthreads();  // vmcnt(0) drain + barrier: staged data visible to all waves

#pragma unroll
    for (int kc = 0; kc < 8; kc++) {
      bf16x8 av[4];
#pragma unroll
      for (int i = 0; i < 4; i++)
        av[i] = *(const bf16x8*)(lA + (kc * 128 + wr * 64 + i * 16 + l15) * 32 + q * 8);
#pragma unroll
      for (int j = 0; j < 8; j++) {
        const bf16x8 bv =
            *(const bf16x8*)(wf + ((long)((wc * 8 + j) * 8 + kc) * 64 + lane) * 8);
#pragma unroll
        for (int i = 0; i < 4; i++)
          acc[i][j] = __builtin_amdgcn_mfma_f32_16x16x32_bf16(av[i], bv,
                                                              acc[i][j], 0, 0, 0);
      }
    }
  }

  // epilogue: C/D layout col=lane&15, row=quad*4+reg (verified m89/m91)
  const int nb = wc * 128 + l15;
  const int mb = mtile * 128 + wr * 64 + q * 4;
  if (mode == 3) {
#pragma unroll
    for (int j = 0; j < 8; j++) {
      const int n = nb + j * 16;
      const float bv = jb.bias ? jb.bias[n] : 0.0f;
#pragma unroll
      for (int i = 0; i < 4; i++) {
        const int m0 = mb + i * 16;
#pragma unroll
        for (int r = 0; r < 4; r++)
          atomicAdd(jb.out + (long)(m0 + r) * 256 + n, acc[i][j][r] + bv);
      }
    }
  } else if (mode == 2) {
#pragma unroll
    for (int j = 0; j < 8; j++) {
      const int n = nb + j * 16;
      const float bv = jb.bias[n];
#pragma unroll
      for (int i = 0; i < 4; i++) {
        const int m0 = mb + i * 16;
#pragma unroll
        for (int r = 0; r < 4; r++) {
          const int m = m0 + r;  // b*4096 + h2*64 + w2
          const int b = m >> 12;
          const int h2 = (m >> 6) & 63;
          const int w2 = m & 63;
          const float val = acc[i][j][r] + bv;
          float* o = jb.out + ((long)(b * 128 + 2 * h2) * 128 + 2 * w2) * 256 + n;
          o[0] = val;
          o[256] = val;
          o[32768] = val;
          o[32768 + 256] = val;
        }
      }
    }
  } else {
#pragma unroll
    for (int j = 0; j < 8; j++) {
      const int n = nb + j * 16;
      const float bv = jb.bias[n];
#pragma unroll
      for (int i = 0; i < 4; i++) {
        const int m0 = mb + i * 16;
#pragma unroll
        for (int r = 0; r < 4; r++)
          jb.out[(long)(m0 + r) * 256 + n] = acc[i][j][r] + bv;
      }
    }
  }
}

extern "C" void kernel_launch(void* const* d_in, const int* in_sizes, int n_in,
                              void* d_out, int out_size, void* d_ws,
                              size_t ws_size, hipStream_t stream) {
  (void)in_sizes; (void)n_in; (void)out_size; (void)ws_size;
  const float* x1 = (const float*)d_in[0];
  const float* x2 = (const float*)d_in[1];
  float* out = (float*)d_out;

  // ws layout (bf16 elements)
  uint16_t* x1p = (uint16_t*)d_ws;  // [2][130][130][256] = 8,652,800
  uint16_t* x2b = x1p + 8652800;    // [2][64][64][256]   = 2,097,152
  uint16_t* wf = x2b + 2097152;     // 16 x 65536 frag-major = 1,048,576

  hipMemsetAsync(x1p, 0, 8652800 * sizeof(uint16_t), stream);      // pad ring
  hipMemsetAsync(out + 29360128L, 0, 2097152 * sizeof(float), stream);  // k_down accum

  nchw2nhwc_v2<<<dim3(2, 4, 256), 256, 0, stream>>>(x1, x1p, 128, 128, 1);
  nchw2nhwc_v2<<<dim3(1, 4, 128), 256, 0, stream>>>(x2, x2b, 64, 64, 0);

  WArgs wa;
  wa.w1[0] = (const float*)d_in[2];   // q1_w
  wa.w1[1] = (const float*)d_in[4];   // q2_w
  wa.w1[2] = (const float*)d_in[6];   // ks1_w
  wa.w1[3] = (const float*)d_in[8];   // ks2_w
  wa.w1[4] = (const float*)d_in[10];  // kup_w
  wa.w1[5] = (const float*)d_in[12];  // v1_w
  wa.w1[6] = (const float*)d_in[14];  // v2_w
  wa.kdw = (const float*)d_in[16];    // kdown_w
  convert_weights_v2<<<512, 256, 0, stream>>>(wa, wf);

  // d_out float offsets (tuple order):
  // q1:0 q2:8388608 k_up:10485760 k_self1:18874368 k_self2:27262976
  // k_down:29360128 v1:31457280 v2:39845888
  const uint16_t* wfk = wf + 7 * 65536;
  JobArgs ja;
  ja.j[0] = {x1p, wfk, (const float*)d_in[17], out + 29360128L, 64, 3, 0};
  ja.j[1] = {x1p, wfk, nullptr,                out + 29360128L, 64, 3, 3};
  ja.j[2] = {x1p, wfk, nullptr,                out + 29360128L, 64, 3, 6};
  ja.j[3] = {x1p, wf + 0 * 65536, (const float*)d_in[3],  out + 0L,        256, 0, 0};  // q1
  ja.j[4] = {x1p, wf + 2 * 65536, (const float*)d_in[7],  out + 18874368L, 256, 0, 0};  // ks1
  ja.j[5] = {x1p, wf + 5 * 65536, (const float*)d_in[13], out + 31457280L, 256, 0, 0};  // v1
  ja.j[6] = {x2b, wf + 4 * 65536, (const float*)d_in[11], out + 10485760L, 64, 2, 0};   // kup
  ja.j[7] = {x2b, wf + 1 * 65536, (const float*)d_in[5],  out + 8388608L,  64, 1, 0};   // q2
  ja.j[8] = {x2b, wf + 3 * 65536, (const float*)d_in[9],  out + 27262976L, 64, 1, 0};   // ks2
  ja.j[9] = {x2b, wf + 6 * 65536, (const float*)d_in[15], out + 39845888L, 64, 1, 0};   // v2
  fused_gemm<<<dim3(256, 1, 10), 256, 0, stream>>>(ja);
}

// Round 3
// 286.447 us; speedup vs baseline: 1.0440x; 1.0440x over previous
//
#include <hip/hip_runtime.h>
#include <hip/hip_bf16.h>
#include <stdint.h>

// FPNAttentionV2 v3: 3 dispatches total. No memsets, no atomics.
//   prep:       f32->bf16 frag-major weights + zero x1p pad ring
//   transpose:  NCHW f32 -> NHWC bf16 (x1 padded + x2), vectorized
//   fused_gemm: flat-indexed jobs; 1x1 convs as 128x256-tile GEMMs (full K in LDS,
//               one barrier pair); kdown as 64x128-tile full-K=2304 GEMM (9 taps).

typedef __attribute__((ext_vector_type(8))) __bf16 bf16x8;
typedef __attribute__((ext_vector_type(4))) float f32x4;
typedef __attribute__((ext_vector_type(8))) unsigned short u16x8;

typedef const __attribute__((address_space(1))) uint32_t* gptr_t;
typedef __attribute__((address_space(3))) uint32_t* lptr_t;

__device__ __forceinline__ void cp16(void* lds, const void* g) {
  // async global->LDS, 16B/lane; LDS dest wave-uniform (HW adds lane*16)
  gptr_t gp = reinterpret_cast<gptr_t>(reinterpret_cast<uintptr_t>(g));
  lptr_t lp = reinterpret_cast<lptr_t>(
      static_cast<uint32_t>(reinterpret_cast<uintptr_t>(lds)));
  __builtin_amdgcn_global_load_lds(gp, lp, 16, 0, 0);
}

// ---------------- prep: weights f32 -> bf16 frag-major, + x1p ring zero ----------------
// Frag-major per matrix (65536 elems): [jg(16)][kc(8)][lane(64)][e(8)]
//   o = jg*16 + (lane&15), k = kc*32 + (lane>>4)*8 + e
// Matrices 0..6: q1,q2,ks1,ks2,kup,v1,v2 ; 7..15: kdown taps 0..8
struct WArgs {
  const float* w1[7];
  const float* kdw;  // [256][256][3][3]
};

__global__ void prep(WArgs a, uint16_t* __restrict__ wf,
                     uint16_t* __restrict__ x1p) {
  const int bx = blockIdx.x;
  if (bx < 512) {
    const int idx = bx * 256 + threadIdx.x;  // 131072
    const int mat = idx >> 13;
    const int g = idx & 8191;
    const int jg = g >> 9;
    const int kc = (g >> 6) & 7;
    const int lane = g & 63;
    const int o = jg * 16 + (lane & 15);
    const int k0 = kc * 32 + (lane >> 4) * 8;
    float f[8];
    if (mat < 7) {
      const float* w = a.w1[mat];
      const float4 v0 = *(const float4*)(w + o * 256 + k0);
      const float4 v1 = *(const float4*)(w + o * 256 + k0 + 4);
      f[0] = v0.x; f[1] = v0.y; f[2] = v0.z; f[3] = v0.w;
      f[4] = v1.x; f[5] = v1.y; f[6] = v1.z; f[7] = v1.w;
    } else {
      const int tap = mat - 7;
#pragma unroll
      for (int e = 0; e < 8; e++)
        f[e] = a.kdw[(long)o * 2304 + (long)(k0 + e) * 9 + tap];
    }
    u16x8 u;
#pragma unroll
    for (int e = 0; e < 8; e++) {
      __hip_bfloat16 hb = __float2bfloat16(f[e]);
      u[e] = *reinterpret_cast<uint16_t*>(&hb);
    }
    *(u16x8*)(wf + (long)idx * 8) = u;
  } else {
    // zero the pad ring of x1p [2][130][130][256]; 33024 16B-chunks
    const int c = (bx - 512) * 256 + threadIdx.x;
    const int b = (c >= 16512) ? 1 : 0;
    const int cc = c - b * 16512;
    int h, w, g8;
    if (cc < 4160) {
      h = 0; w = cc >> 5; g8 = cc & 31;
    } else if (cc < 8320) {
      const int s = cc - 4160; h = 129; w = s >> 5; g8 = s & 31;
    } else if (cc < 12416) {
      const int s = cc - 8320; h = 1 + (s >> 5); w = 0; g8 = s & 31;
    } else {
      const int s = cc - 12416; h = 1 + (s >> 5); w = 129; g8 = s & 31;
    }
    u16x8 z = {};
    *(u16x8*)(x1p + (((long)(b * 130 + h)) * 130 + w) * 256 + g8 * 8) = z;
  }
}

// ---------------- NCHW f32 -> NHWC bf16 (x1 with pad ring, x2 plain) ----------------
// grid dim3(2,4,384): z<256 -> x1 (b*128+h); z>=256 -> x2 (b*64+h, only x==0)
__global__ void transpose_all(const float* __restrict__ x1,
                              const float* __restrict__ x2,
                              uint16_t* __restrict__ x1p,
                              uint16_t* __restrict__ x2b) {
  const float* src;
  uint16_t* dst;
  int H, W, pad, b, h;
  if ((int)blockIdx.z < 256) {
    src = x1; dst = x1p; H = 128; W = 128; pad = 1;
    b = blockIdx.z >> 7; h = blockIdx.z & 127;
  } else {
    if (blockIdx.x) return;
    const int t = blockIdx.z - 256;
    src = x2; dst = x2b; H = 64; W = 64; pad = 0;
    b = t >> 6; h = t & 63;
  }
  __shared__ float tile[64][65];
  const int tid = threadIdx.x;
  const int wt = blockIdx.x * 64;
  const int ct = blockIdx.y * 64;
  const long cs = (long)H * W;
  const float* s = src + ((long)(b * 256 + ct) * H + h) * W + wt;
  const int rw = tid >> 4;
  const int rf = tid & 15;
#pragma unroll
  for (int p = 0; p < 4; p++) {
    const int cl = p * 16 + rw;
    const float4 v = *(const float4*)(s + (long)cl * cs + rf * 4);
    tile[cl][rf * 4 + 0] = v.x;
    tile[cl][rf * 4 + 1] = v.y;
    tile[cl][rf * 4 + 2] = v.z;
    tile[cl][rf * 4 + 3] = v.w;
  }
  __syncthreads();
  const int wl0 = tid >> 3;
  const int cg = tid & 7;
  const int Wp = W + 2 * pad;
  const long rowb = ((long)(b * (H + 2 * pad) + h + pad)) * Wp + pad + wt;
#pragma unroll
  for (int p = 0; p < 2; p++) {
    const int wl = p * 32 + wl0;
    u16x8 u;
#pragma unroll
    for (int k = 0; k < 8; k++) {
      __hip_bfloat16 hb = __float2bfloat16(tile[cg * 8 + k][wl]);
      u[k] = *reinterpret_cast<uint16_t*>(&hb);
    }
    *(u16x8*)(dst + (rowb + wl) * 256 + ct + cg * 8) = u;
  }
}

// ---------------- fused GEMM ----------------
struct Job {
  const uint16_t* A;
  const uint16_t* Wf;
  const float* bias;
  float* out;
  int start;  // first flat block id
  int mode;   // 0: x1 1x1, 1: x2 1x1, 2: x2 + 2x upsample, 3: kdown 3x3s2
};
struct JobArgs {
  Job j[8];
};

// block 256 = 4 waves (2x2). Modes 0-2: tile 128x256, full K=256 in LDS (64KB), one
// barrier pair. Mode 3: tile 64x128, 9 taps (K=2304), 32KB stage per tap, plain stores.
__global__ __launch_bounds__(256, 2) void fused_gemm(JobArgs args) {
  int jid = 0;
#pragma unroll
  for (int t = 1; t < 8; t++)
    if ((int)blockIdx.x >= args.j[t].start) jid = t;
  const Job jb = args.j[jid];
  const int bid = blockIdx.x - jb.start;
  const int mode = jb.mode;

  __shared__ __align__(16) uint16_t lA[32768];  // 64KB

  const int tid = threadIdx.x;
  const int lane = tid & 63;
  const int wave = tid >> 6;
  const int wr = wave & 1;
  const int wc = wave >> 1;
  const int q = lane >> 4;
  const int l15 = lane & 15;

  if (mode == 3) {
    // ---- kdown: 64x128 tile, mtile = bid>>1, ntile = bid&1 ----
    const int mtile = bid >> 1;
    const int ntile = bid & 1;
    const int row = mtile * 64 + wave * 16 + (lane >> 2);
    // row = b*4096 + oh*64 + ow -> padded (b, 2oh, 2ow)
    const long p =
        ((long)((row >> 12) * 130 + 2 * ((row >> 6) & 63))) * 130 + 2 * (row & 63);
    const uint16_t* rowA = jb.A + p * 256 + (lane & 3) * 8;

    f32x4 acc[2][4] = {};
    for (int tap = 0; tap < 9; tap++) {
      const int kh = tap / 3;
      const int kw = tap - kh * 3;
      const long aoff = (long)(kh * 130 + kw) * 256;
      const uint16_t* wf = jb.Wf + (long)tap * 65536;
      if (tap) __syncthreads();
#pragma unroll
      for (int kap = 0; kap < 8; kap++)
        cp16(lA + (kap * 256 + wave * 64) * 8, rowA + aoff + kap * 32);
      __syncthreads();
#pragma unroll
      for (int kc = 0; kc < 8; kc++) {
        bf16x8 av[2];
#pragma unroll
        for (int i = 0; i < 2; i++)
          av[i] = *(const bf16x8*)(lA + (kc * 64 + wr * 32 + i * 16 + l15) * 32 + q * 8);
#pragma unroll
        for (int j = 0; j < 4; j++) {
          const bf16x8 bv = *(const bf16x8*)(
              wf + ((long)((ntile * 8 + wc * 4 + j) * 8 + kc) * 64 + lane) * 8);
#pragma unroll
          for (int i = 0; i < 2; i++)
            acc[i][j] = __builtin_amdgcn_mfma_f32_16x16x32_bf16(av[i], bv,
                                                                acc[i][j], 0, 0, 0);
        }
      }
    }
    const int nb = ntile * 128 + wc * 64 + l15;
    const int mb = mtile * 64 + wr * 32 + q * 4;
#pragma unroll
    for (int j = 0; j < 4; j++) {
      const int n = nb + j * 16;
      const float bvs = jb.bias[n];
#pragma unroll
      for (int i = 0; i < 2; i++) {
        const int m0 = mb + i * 16;
#pragma unroll
        for (int r = 0; r < 4; r++)
          jb.out[(long)(m0 + r) * 256 + n] = acc[i][j][r] + bvs;
      }
    }
    return;
  }

  // ---- 1x1 convs: tile 128x256, full K staged once ----
  const int mtile = bid;
  const uint16_t* rowA[2];
  {
    const int rbase = wave * 16 + (lane >> 2);
#pragma unroll
    for (int rh = 0; rh < 2; rh++) {
      const int m = mtile * 128 + rh * 64 + rbase;
      long p;
      if (mode == 0) {
        p = ((long)((m >> 14) * 130 + ((m >> 7) & 127) + 1)) * 130 + (m & 127) + 1;
      } else {
        p = m;
      }
      rowA[rh] = jb.A + p * 256 + (lane & 3) * 8;
    }
  }

  // stage 64KB: [kc(8)][row(128)][32 elems]
#pragma unroll
  for (int kap = 0; kap < 16; kap++)
    cp16(lA + (kap * 256 + wave * 64) * 8, rowA[kap & 1] + (kap >> 1) * 32);
  __syncthreads();

  f32x4 acc[4][8] = {};
#pragma unroll
  for (int kc = 0; kc < 8; kc++) {
    bf16x8 av[4];
#pragma unroll
    for (int i = 0; i < 4; i++)
      av[i] = *(const bf16x8*)(lA + (kc * 128 + wr * 64 + i * 16 + l15) * 32 + q * 8);
#pragma unroll
    for (int j = 0; j < 8; j++) {
      const bf16x8 bv =
          *(const bf16x8*)(jb.Wf + ((long)((wc * 8 + j) * 8 + kc) * 64 + lane) * 8);
#pragma unroll
      for (int i = 0; i < 4; i++)
        acc[i][j] = __builtin_amdgcn_mfma_f32_16x16x32_bf16(av[i], bv,
                                                            acc[i][j], 0, 0, 0);
    }
  }

  // epilogue: C/D layout col=lane&15, row=quad*4+reg
  const int nb = wc * 128 + l15;
  const int mb = mtile * 128 + wr * 64 + q * 4;
  if (mode == 2) {
#pragma unroll
    for (int j = 0; j < 8; j++) {
      const int n = nb + j * 16;
      const float bvs = jb.bias[n];
#pragma unroll
      for (int i = 0; i < 4; i++) {
        const int m0 = mb + i * 16;
#pragma unroll
        for (int r = 0; r < 4; r++) {
          const int m = m0 + r;  // b*4096 + h2*64 + w2
          const int b = m >> 12;
          const int h2 = (m >> 6) & 63;
          const int w2 = m & 63;
          const float val = acc[i][j][r] + bvs;
          float* o =
              jb.out + ((long)(b * 128 + 2 * h2) * 128 + 2 * w2) * 256 + n;
          o[0] = val;
          o[256] = val;
          o[32768] = val;
          o[32768 + 256] = val;
        }
      }
    }
  } else {
#pragma unroll
    for (int j = 0; j < 8; j++) {
      const int n = nb + j * 16;
      const float bvs = jb.bias[n];
#pragma unroll
      for (int i = 0; i < 4; i++) {
        const int m0 = mb + i * 16;
#pragma unroll
        for (int r = 0; r < 4; r++)
          jb.out[(long)(m0 + r) * 256 + n] = acc[i][j][r] + bvs;
      }
    }
  }
}

extern "C" void kernel_launch(void* const* d_in, const int* in_sizes, int n_in,
                              void* d_out, int out_size, void* d_ws,
                              size_t ws_size, hipStream_t stream) {
  (void)in_sizes; (void)n_in; (void)out_size; (void)ws_size;
  const float* x1 = (const float*)d_in[0];
  const float* x2 = (const float*)d_in[1];
  float* out = (float*)d_out;

  uint16_t* x1p = (uint16_t*)d_ws;  // [2][130][130][256] = 8,652,800
  uint16_t* x2b = x1p + 8652800;    // [2][64][64][256]   = 2,097,152
  uint16_t* wf = x2b + 2097152;     // 16 x 65536 frag-major

  WArgs wa;
  wa.w1[0] = (const float*)d_in[2];   // q1_w
  wa.w1[1] = (const float*)d_in[4];   // q2_w
  wa.w1[2] = (const float*)d_in[6];   // ks1_w
  wa.w1[3] = (const float*)d_in[8];   // ks2_w
  wa.w1[4] = (const float*)d_in[10];  // kup_w
  wa.w1[5] = (const float*)d_in[12];  // v1_w
  wa.w1[6] = (const float*)d_in[14];  // v2_w
  wa.kdw = (const float*)d_in[16];    // kdown_w
  prep<<<641, 256, 0, stream>>>(wa, wf, x1p);
  transpose_all<<<dim3(2, 4, 384), 256, 0, stream>>>(x1, x2, x1p, x2b);

  // d_out float offsets (tuple order):
  // q1:0 q2:8388608 k_up:10485760 k_self1:18874368 k_self2:27262976
  // k_down:29360128 v1:31457280 v2:39845888
  JobArgs ja;
  ja.j[0] = {x1p, wf + 7 * 65536, (const float*)d_in[17], out + 29360128L, 0,    3};  // kdown
  ja.j[1] = {x1p, wf + 0 * 65536, (const float*)d_in[3],  out + 0L,        256,  0};  // q1
  ja.j[2] = {x1p, wf + 2 * 65536, (const float*)d_in[7],  out + 18874368L, 512,  0};  // ks1
  ja.j[3] = {x1p, wf + 5 * 65536, (const float*)d_in[13], out + 31457280L, 768,  0};  // v1
  ja.j[4] = {x2b, wf + 4 * 65536, (const float*)d_in[11], out + 10485760L, 1024, 2};  // kup
  ja.j[5] = {x2b, wf + 1 * 65536, (const float*)d_in[5],  out + 8388608L,  1088, 1};  // q2
  ja.j[6] = {x2b, wf + 3 * 65536, (const float*)d_in[9],  out + 27262976L, 1152, 1};  // ks2
  ja.j[7] = {x2b, wf + 6 * 65536, (const float*)d_in[15], out + 39845888L, 1216, 1};  // v2
  fused_gemm<<<1280, 256, 0, stream>>>(ja);
}